// Round 12
// baseline (395.462 us; speedup 1.0000x reference)
//
#include <hip/hip_runtime.h>
#include <hip/hip_bf16.h>

#define KK 32
#define L2E 1.4426950408889634f
#define LOG2_INV_SQRT_2PI -1.3257480647361593f   // log2(1/sqrt(2*pi))

// Dual-dtype element load: bf16 (halfword<<16) or fp32, per runtime flag.
__device__ __forceinline__ float ld_elem(const void* p, int i, bool isb) {
    if (isb) {
        unsigned int u = ((unsigned int)((const unsigned short*)p)[i]) << 16;
        return __uint_as_float(u);
    }
    return ((const float*)p)[i];
}

__device__ __forceinline__ unsigned int pack_bf16(float lo, float hi) {
    unsigned int ulo = (__float_as_uint(lo) + 0x8000u) >> 16;
    unsigned int uhi = (__float_as_uint(hi) + 0x8000u) & 0xffff0000u;
    return ulo | uhi;
}

// Prep: detect dtype, softmaxes in log2 domain, fold into MONOMIAL quadratics:
//   w21·pdf(x1)    = exp2(α·x1² + β·x1 + γ1)
//   w10·w0·pdf(x0) = exp2(α·x0² + β·x0 + γ2)
__global__ __launch_bounds__(256) void ttg_prep(
    const void* __restrict__ Wk0,
    const void* __restrict__ W10,
    const void* __restrict__ W21,
    const void* __restrict__ mu,
    const void* __restrict__ sigma,
    float4* __restrict__ tabF, int* __restrict__ flag) {
    __shared__ float sW0[KK];
    __shared__ float sW10[KK * KK];
    __shared__ float sW21[KK * KK];
    __shared__ float sMu[KK * KK];
    __shared__ float sSg[KK * KK];

    const int t = threadIdx.x;
    const int j = t & 31;

    // dtype detection: genuine bf16 sigma in (0.3,0.8); fp32-as-bf16 even
    // halfwords are mantissa garbage.
    bool isb = true;
#pragma unroll
    for (int k = 0; k < 16; k++) {
        unsigned int u = ((unsigned int)((const unsigned short*)sigma)[k]) << 16;
        float v = __uint_as_float(u);
        if (!(v > 0.3f && v < 0.8f)) isb = false;   // NaN-safe
    }

#pragma unroll
    for (int q = 0; q < 4; q++) {
        const int e = t + q * 256;
        sW10[e] = ld_elem(W10, e, isb);
        sW21[e] = ld_elem(W21, e, isb);
        sMu[e]  = ld_elem(mu, e, isb);
        sSg[e]  = ld_elem(sigma, e, isb);
    }
    if (t < KK) sW0[t] = ld_elem(Wk0, t, isb);
    __syncthreads();

    float m0 = -1e30f;
#pragma unroll
    for (int k = 0; k < KK; k++) m0 = fmaxf(m0, sW0[k]);
    float d0 = 0.f;
#pragma unroll
    for (int k = 0; k < KK; k++) d0 += __builtin_amdgcn_exp2f((sW0[k] - m0) * L2E);
    const float l2d0 = __builtin_amdgcn_logf(d0);
    const float lw0j = (sW0[j] - m0) * L2E - l2d0;          // log2(w0[j])

    float m10 = -1e30f, m21 = -1e30f;
#pragma unroll
    for (int k = 0; k < KK; k++) {
        m10 = fmaxf(m10, sW10[k * KK + j]);
        m21 = fmaxf(m21, sW21[k * KK + j]);
    }
    float d10 = 0.f, d21 = 0.f;
#pragma unroll
    for (int k = 0; k < KK; k++) {
        d10 += __builtin_amdgcn_exp2f((sW10[k * KK + j] - m10) * L2E);
        d21 += __builtin_amdgcn_exp2f((sW21[k * KK + j] - m21) * L2E);
    }
    const float l2d10 = __builtin_amdgcn_logf(d10);
    const float l2d21 = __builtin_amdgcn_logf(d21);

#pragma unroll
    for (int q = 0; q < 4; q++) {
        const int e = t + q * 256;          // entry (a, b=j)
        const int a = e >> 5;
        const float mu_v = sMu[e];
        const float sg   = sSg[e];
        const float is   = 1.0f / sg;
        const float alpha = -0.5f * L2E * is * is;
        const float beta  = -2.0f * alpha * mu_v;
        const float g0    = alpha * mu_v * mu_v
                          + LOG2_INV_SQRT_2PI + __builtin_amdgcn_logf(is);
        const float lw21 = (sW21[a * KK + j] - m21) * L2E - l2d21;
        const float lw10 = (sW10[a * KK + j] - m10) * L2E - l2d10;
        tabF[e] = make_float4(alpha, beta, g0 + lw21, g0 + lw10 + lw0j);
    }

    if (t == 0) *flag = isb ? 1 : 0;
}

// Main: TWO samples per lane (block = 128 samples), 4 waves split the 32 rows.
// R11 arithmetic: the sweep was LDS-pipe-bound — 6.1 blocks/CU x 1024
// broadcast ds_read_b128 x ~12cyc ≈ 31us ≈ measured main. Halving blocks
// (2 samples/lane per ds_read) halves per-CU DS demand -> ~15.6us, above
// trans (10.4us) and VALU (7.8us) demand. Accumulators 2x(32+8)=80 VGPR ->
// launch_bounds(256,3) (grid only needs 3.05 waves/SIMD). Exchange runs
// twice sequentially in the sTab overlay (no LDS growth, R10 lesson: no LDS
// writes inside the sweep).
__global__ __launch_bounds__(256, 3) void ttg_main(
    const void* __restrict__ X,
    const float4* __restrict__ tabF,
    const int* __restrict__ flag,
    void* __restrict__ out, int N) {
    __shared__ alignas(16) char smem[17408];
    float4* sTab = (float4*)smem;                                   // [0,16K) sweep
    unsigned int (*sCp)[16][64] = (unsigned int (*)[16][64])smem;   // [0,16K) post
    float (*sLik)[64] = (float (*)[64])(smem + 16384);              // [16K,17K)

    const int tid  = threadIdx.x;
    const int lane = tid & 63;
    const int w    = __builtin_amdgcn_readfirstlane(tid >> 6);   // wave id, scalar
    const int base = blockIdx.x * 128;
    const int s0   = base + lane;         // sample A
    const int s1   = base + 64 + lane;    // sample B
    const int n0 = s0 < N ? s0 : N - 1;
    const int n1 = s1 < N ? s1 : N - 1;

    const bool isb = (*flag != 0);

    // Stage table (coalesced: 4 float4 per thread)
#pragma unroll
    for (int q = 0; q < 4; q++) {
        const int e = q * 256 + tid;
        sTab[e] = tabF[e];
    }

    float xA0, xA1, xB0, xB1;
    if (isb) {
        const __hip_bfloat162 pa = ((const __hip_bfloat162*)X)[n0];
        const __hip_bfloat162 pb = ((const __hip_bfloat162*)X)[n1];
        xA0 = __bfloat162float(pa.x);  xA1 = __bfloat162float(pa.y);
        xB0 = __bfloat162float(pb.x);  xB1 = __bfloat162float(pb.y);
    } else {
        const float2 pa = ((const float2*)X)[n0];
        const float2 pb = ((const float2*)X)[n1];
        xA0 = pa.x;  xA1 = pa.y;
        xB0 = pb.x;  xB1 = pb.y;
    }
    __syncthreads();

    const float xA1s = xA1 * xA1, xA0s = xA0 * xA0;
    const float xB1s = xB1 * xB1, xB0s = xB0 * xB0;

    float inA[KK], inB[KK];   // partial inner[b] over rows [8w, 8w+8)
    float sA[8], sB[8];       // S2[8w+a2]
#pragma unroll
    for (int b = 0; b < KK; b++) { inA[b] = 0.f; inB[b] = 0.f; }
#pragma unroll
    for (int a2 = 0; a2 < 8; a2++) { sA[a2] = 0.f; sB[a2] = 0.f; }

#pragma unroll
    for (int a2 = 0; a2 < 8; ++a2) {
#pragma unroll
        for (int b = 0; b < KK; ++b) {
            const float4 c = sTab[(w * 8 + a2) * KK + b];  // ONE broadcast read, 2 samples
            inA[b] += __builtin_amdgcn_exp2f(fmaf(c.x, xA1s, fmaf(c.y, xA1, c.z)));
            sA[a2] += __builtin_amdgcn_exp2f(fmaf(c.x, xA0s, fmaf(c.y, xA0, c.w)));
            inB[b] += __builtin_amdgcn_exp2f(fmaf(c.x, xB1s, fmaf(c.y, xB1, c.z)));
            sB[a2] += __builtin_amdgcn_exp2f(fmaf(c.x, xB0s, fmaf(c.y, xB0, c.w)));
        }
    }
    __syncthreads();   // sweep done everywhere; sTab dead -> sCp may overlay

    // ---- epilogue, sample A ----
#pragma unroll
    for (int p = 0; p < 16; ++p)
        sCp[w][p][lane] = pack_bf16(inA[2 * p], inA[2 * p + 1]);
    __syncthreads();
    {
        float lik = 0.f;
#pragma unroll
        for (int pp = 0; pp < 4; ++pp) {
            const int p = 4 * w + pp;
            float fLo = 0.f, fHi = 0.f;
#pragma unroll
            for (int w2 = 0; w2 < 4; ++w2) {
                const unsigned int u = sCp[w2][p][lane];
                fLo += __uint_as_float(u << 16);
                fHi += __uint_as_float(u & 0xffff0000u);
            }
            lik = fmaf(sA[2 * pp],     fLo, lik);
            lik = fmaf(sA[2 * pp + 1], fHi, lik);
        }
        sLik[w][lane] = lik;
    }
    __syncthreads();
    if (w == 0) {
        float tot = (sLik[0][lane] + sLik[1][lane]) + (sLik[2][lane] + sLik[3][lane]);
        tot = fmaxf(tot, 0.0f);
        const float res = __builtin_amdgcn_logf(tot + 2.2204460492503131e-16f)
                          * 0.6931471805599453f;
        if (s0 < N) {
            if (isb) ((__hip_bfloat16*)out)[s0] = __float2bfloat16(res);
            else     ((float*)out)[s0] = res;
        }
    }
    // sCp(s0) reads all completed before the sync above; safe to repack.

    // ---- epilogue, sample B ----
#pragma unroll
    for (int p = 0; p < 16; ++p)
        sCp[w][p][lane] = pack_bf16(inB[2 * p], inB[2 * p + 1]);
    __syncthreads();
    {
        float lik = 0.f;
#pragma unroll
        for (int pp = 0; pp < 4; ++pp) {
            const int p = 4 * w + pp;
            float fLo = 0.f, fHi = 0.f;
#pragma unroll
            for (int w2 = 0; w2 < 4; ++w2) {
                const unsigned int u = sCp[w2][p][lane];
                fLo += __uint_as_float(u << 16);
                fHi += __uint_as_float(u & 0xffff0000u);
            }
            lik = fmaf(sB[2 * pp],     fLo, lik);
            lik = fmaf(sB[2 * pp + 1], fHi, lik);
        }
        sLik[w][lane] = lik;
    }
    __syncthreads();
    if (w == 0) {
        float tot = (sLik[0][lane] + sLik[1][lane]) + (sLik[2][lane] + sLik[3][lane]);
        tot = fmaxf(tot, 0.0f);
        const float res = __builtin_amdgcn_logf(tot + 2.2204460492503131e-16f)
                          * 0.6931471805599453f;
        if (s1 < N) {
            if (isb) ((__hip_bfloat16*)out)[s1] = __float2bfloat16(res);
            else     ((float*)out)[s1] = res;
        }
    }
}

extern "C" void kernel_launch(void* const* d_in, const int* in_sizes, int n_in,
                              void* d_out, int out_size, void* d_ws, size_t ws_size,
                              hipStream_t stream) {
    const void* X     = d_in[0];
    const void* Wk0   = d_in[1];
    const void* W10   = d_in[2];
    const void* W21   = d_in[3];
    const void* mu    = d_in[4];
    const void* sigma = d_in[5];

    float4* tabF = (float4*)d_ws;                  // 1024 x 16B = 16 KB
    int*    flag = (int*)((char*)d_ws + 1024 * sizeof(float4));

    const int N = in_sizes[0] / 2;

    ttg_prep<<<1, 256, 0, stream>>>(Wk0, W10, W21, mu, sigma, tabF, flag);
    // 128 samples per 256-thread block (2 per lane); 4 waves split the 32 rows
    ttg_main<<<(N + 127) / 128, 256, 0, stream>>>(X, tabF, flag, d_out, N);
}

// Round 13
// 105.109 us; speedup vs baseline: 3.7624x; 3.7624x over previous
//
#include <hip/hip_runtime.h>
#include <hip/hip_bf16.h>

#define KK 32
#define L2E 1.4426950408889634f
#define LOG2_INV_SQRT_2PI -1.3257480647361593f   // log2(1/sqrt(2*pi))

// Dual-dtype element load: bf16 (halfword<<16) or fp32, per runtime flag.
__device__ __forceinline__ float ld_elem(const void* p, int i, bool isb) {
    if (isb) {
        unsigned int u = ((unsigned int)((const unsigned short*)p)[i]) << 16;
        return __uint_as_float(u);
    }
    return ((const float*)p)[i];
}

__device__ __forceinline__ unsigned int pack_bf16(float lo, float hi) {
    unsigned int ulo = (__float_as_uint(lo) + 0x8000u) >> 16;
    unsigned int uhi = (__float_as_uint(hi) + 0x8000u) & 0xffff0000u;
    return ulo | uhi;
}

// Prep: detect dtype, softmaxes in log2 domain, fold into MONOMIAL quadratics:
//   w21·pdf(x1)    = exp2(α·x1² + β·x1 + γ1)
//   w10·w0·pdf(x0) = exp2(α·x0² + β·x0 + γ2)
__global__ __launch_bounds__(256) void ttg_prep(
    const void* __restrict__ Wk0,
    const void* __restrict__ W10,
    const void* __restrict__ W21,
    const void* __restrict__ mu,
    const void* __restrict__ sigma,
    float4* __restrict__ tabF, int* __restrict__ flag) {
    __shared__ float sW0[KK];
    __shared__ float sW10[KK * KK];
    __shared__ float sW21[KK * KK];
    __shared__ float sMu[KK * KK];
    __shared__ float sSg[KK * KK];

    const int t = threadIdx.x;
    const int j = t & 31;

    // dtype detection: genuine bf16 sigma in (0.3,0.8); fp32-as-bf16 even
    // halfwords are mantissa garbage.
    bool isb = true;
#pragma unroll
    for (int k = 0; k < 16; k++) {
        unsigned int u = ((unsigned int)((const unsigned short*)sigma)[k]) << 16;
        float v = __uint_as_float(u);
        if (!(v > 0.3f && v < 0.8f)) isb = false;   // NaN-safe
    }

#pragma unroll
    for (int q = 0; q < 4; q++) {
        const int e = t + q * 256;
        sW10[e] = ld_elem(W10, e, isb);
        sW21[e] = ld_elem(W21, e, isb);
        sMu[e]  = ld_elem(mu, e, isb);
        sSg[e]  = ld_elem(sigma, e, isb);
    }
    if (t < KK) sW0[t] = ld_elem(Wk0, t, isb);
    __syncthreads();

    float m0 = -1e30f;
#pragma unroll
    for (int k = 0; k < KK; k++) m0 = fmaxf(m0, sW0[k]);
    float d0 = 0.f;
#pragma unroll
    for (int k = 0; k < KK; k++) d0 += __builtin_amdgcn_exp2f((sW0[k] - m0) * L2E);
    const float l2d0 = __builtin_amdgcn_logf(d0);
    const float lw0j = (sW0[j] - m0) * L2E - l2d0;          // log2(w0[j])

    float m10 = -1e30f, m21 = -1e30f;
#pragma unroll
    for (int k = 0; k < KK; k++) {
        m10 = fmaxf(m10, sW10[k * KK + j]);
        m21 = fmaxf(m21, sW21[k * KK + j]);
    }
    float d10 = 0.f, d21 = 0.f;
#pragma unroll
    for (int k = 0; k < KK; k++) {
        d10 += __builtin_amdgcn_exp2f((sW10[k * KK + j] - m10) * L2E);
        d21 += __builtin_amdgcn_exp2f((sW21[k * KK + j] - m21) * L2E);
    }
    const float l2d10 = __builtin_amdgcn_logf(d10);
    const float l2d21 = __builtin_amdgcn_logf(d21);

#pragma unroll
    for (int q = 0; q < 4; q++) {
        const int e = t + q * 256;          // entry (a, b=j)
        const int a = e >> 5;
        const float mu_v = sMu[e];
        const float sg   = sSg[e];
        const float is   = 1.0f / sg;
        const float alpha = -0.5f * L2E * is * is;
        const float beta  = -2.0f * alpha * mu_v;
        const float g0    = alpha * mu_v * mu_v
                          + LOG2_INV_SQRT_2PI + __builtin_amdgcn_logf(is);
        const float lw21 = (sW21[a * KK + j] - m21) * L2E - l2d21;
        const float lw10 = (sW10[a * KK + j] - m10) * L2E - l2d10;
        tabF[e] = make_float4(alpha, beta, g0 + lw21, g0 + lw10 + lw0j);
    }

    if (t == 0) *flag = isb ? 1 : 0;
}

// Main: TWO samples per lane (128/block), 4 waves x 8 rows, sweep CHUNKED
// over b in 4 chunks of 8. R12 lesson: 80 persistent accumulators across a
// fully-unrolled 1024-exp2 body -> allocator spills to scratch (156MB FETCH,
// 345us). Here only cA[8]+cB[8] (chunk-local) + sA[8]+sB[8] (persistent) are
// live: peak ~50 regs. Chunk partials leave registers via plain bf16-packed
// ds_writes at chunk boundaries (32 stores/wave — NOT R10's per-entry
// atomics) into a separate exchange region. One ds_read_b128 feeds 2 samples
// -> per-CU DS demand halves vs R11 (the R11 binder: 6.1 blocks x 1024 reads
// x 12cyc ≈ 31us ≈ measured main). LDS 16K tab + 32K exchange = 48K -> 3
// blocks/CU, matching the 3.05 blocks/CU grid.
__global__ __launch_bounds__(256, 4) void ttg_main(
    const void* __restrict__ X,
    const float4* __restrict__ tabF,
    const int* __restrict__ flag,
    void* __restrict__ out, int N) {
    __shared__ alignas(16) char smem[49152];
    float4* sTab = (float4*)smem;                         // [0,16K) dead after sweep
    unsigned int (*sCpA)[4][4][64] =
        (unsigned int (*)[4][4][64])(smem + 16384);       // [16K,32K) [writer][chunk][pair][lane]
    unsigned int (*sCpB)[4][4][64] =
        (unsigned int (*)[4][4][64])(smem + 32768);       // [32K,48K)
    float (*sLikA)[64] = (float (*)[64])smem;             // overlay, post-sweep
    float (*sLikB)[64] = (float (*)[64])(smem + 1024);

    const int tid  = threadIdx.x;
    const int lane = tid & 63;
    const int w    = __builtin_amdgcn_readfirstlane(tid >> 6);   // wave id, scalar
    const int base = blockIdx.x * 128;
    const int s0   = base + lane;         // sample A
    const int s1   = base + 64 + lane;    // sample B
    const int n0 = s0 < N ? s0 : N - 1;
    const int n1 = s1 < N ? s1 : N - 1;

    const bool isb = (*flag != 0);

    // Stage table (coalesced: 4 float4 per thread)
#pragma unroll
    for (int q = 0; q < 4; q++) {
        const int e = q * 256 + tid;
        sTab[e] = tabF[e];
    }

    float xA0, xA1, xB0, xB1;
    if (isb) {
        const __hip_bfloat162 pa = ((const __hip_bfloat162*)X)[n0];
        const __hip_bfloat162 pb = ((const __hip_bfloat162*)X)[n1];
        xA0 = __bfloat162float(pa.x);  xA1 = __bfloat162float(pa.y);
        xB0 = __bfloat162float(pb.x);  xB1 = __bfloat162float(pb.y);
    } else {
        const float2 pa = ((const float2*)X)[n0];
        const float2 pb = ((const float2*)X)[n1];
        xA0 = pa.x;  xA1 = pa.y;
        xB0 = pb.x;  xB1 = pb.y;
    }
    __syncthreads();

    const float xA1s = xA1 * xA1, xA0s = xA0 * xA0;
    const float xB1s = xB1 * xB1, xB0s = xB0 * xB0;

    float sA[8], sB[8];       // S2 partial rows 8w..8w+7 (persistent, 16 regs)
#pragma unroll
    for (int a2 = 0; a2 < 8; a2++) { sA[a2] = 0.f; sB[a2] = 0.f; }

#pragma unroll
    for (int c = 0; c < 4; ++c) {         // b-chunk [8c, 8c+8)
        float cA[8], cB[8];               // chunk-local inner partials
#pragma unroll
        for (int bi = 0; bi < 8; ++bi) { cA[bi] = 0.f; cB[bi] = 0.f; }
#pragma unroll
        for (int a2 = 0; a2 < 8; ++a2) {
#pragma unroll
            for (int bi = 0; bi < 8; ++bi) {
                const float4 cf = sTab[(w * 8 + a2) * KK + c * 8 + bi]; // broadcast b128
                cA[bi] += __builtin_amdgcn_exp2f(fmaf(cf.x, xA1s, fmaf(cf.y, xA1, cf.z)));
                sA[a2] += __builtin_amdgcn_exp2f(fmaf(cf.x, xA0s, fmaf(cf.y, xA0, cf.w)));
                cB[bi] += __builtin_amdgcn_exp2f(fmaf(cf.x, xB1s, fmaf(cf.y, xB1, cf.z)));
                sB[a2] += __builtin_amdgcn_exp2f(fmaf(cf.x, xB0s, fmaf(cf.y, xB0, cf.w)));
            }
        }
        // Chunk partials -> exchange (plain stores, chunk boundary only).
#pragma unroll
        for (int p = 0; p < 4; ++p) {
            sCpA[w][c][p][lane] = pack_bf16(cA[2 * p], cA[2 * p + 1]);
            sCpB[w][c][p][lane] = pack_bf16(cB[2 * p], cB[2 * p + 1]);
        }
    }
    __syncthreads();   // sweep + all exchange writes done; sTab dead

    // Wave w consumes inner[8w..8w+7] = chunk w, summed over the 4 writers.
    float likA = 0.f, likB = 0.f;
#pragma unroll
    for (int p = 0; p < 4; ++p) {         // pair p covers a2 = 2p, 2p+1
        float aLo = 0.f, aHi = 0.f, bLo = 0.f, bHi = 0.f;
#pragma unroll
        for (int w2 = 0; w2 < 4; ++w2) {
            const unsigned int uA = sCpA[w2][w][p][lane];
            const unsigned int uB = sCpB[w2][w][p][lane];
            aLo += __uint_as_float(uA << 16);
            aHi += __uint_as_float(uA & 0xffff0000u);
            bLo += __uint_as_float(uB << 16);
            bHi += __uint_as_float(uB & 0xffff0000u);
        }
        likA = fmaf(sA[2 * p],     aLo, likA);
        likA = fmaf(sA[2 * p + 1], aHi, likA);
        likB = fmaf(sB[2 * p],     bLo, likB);
        likB = fmaf(sB[2 * p + 1], bHi, likB);
    }

    sLikA[w][lane] = likA;                // overlay region (sTab dead)
    sLikB[w][lane] = likB;
    __syncthreads();
    if (w == 0) {
        float totA = (sLikA[0][lane] + sLikA[1][lane]) + (sLikA[2][lane] + sLikA[3][lane]);
        float totB = (sLikB[0][lane] + sLikB[1][lane]) + (sLikB[2][lane] + sLikB[3][lane]);
        totA = fmaxf(totA, 0.0f);
        totB = fmaxf(totB, 0.0f);
        const float rA = __builtin_amdgcn_logf(totA + 2.2204460492503131e-16f)
                         * 0.6931471805599453f;
        const float rB = __builtin_amdgcn_logf(totB + 2.2204460492503131e-16f)
                         * 0.6931471805599453f;
        if (isb) {
            if (s0 < N) ((__hip_bfloat16*)out)[s0] = __float2bfloat16(rA);
            if (s1 < N) ((__hip_bfloat16*)out)[s1] = __float2bfloat16(rB);
        } else {
            if (s0 < N) ((float*)out)[s0] = rA;
            if (s1 < N) ((float*)out)[s1] = rB;
        }
    }
}

extern "C" void kernel_launch(void* const* d_in, const int* in_sizes, int n_in,
                              void* d_out, int out_size, void* d_ws, size_t ws_size,
                              hipStream_t stream) {
    const void* X     = d_in[0];
    const void* Wk0   = d_in[1];
    const void* W10   = d_in[2];
    const void* W21   = d_in[3];
    const void* mu    = d_in[4];
    const void* sigma = d_in[5];

    float4* tabF = (float4*)d_ws;                  // 1024 x 16B = 16 KB
    int*    flag = (int*)((char*)d_ws + 1024 * sizeof(float4));

    const int N = in_sizes[0] / 2;

    ttg_prep<<<1, 256, 0, stream>>>(Wk0, W10, W21, mu, sigma, tabF, flag);
    // 128 samples per 256-thread block (2 per lane); 4 waves split the 32 rows
    ttg_main<<<(N + 127) / 128, 256, 0, stream>>>(X, tabF, flag, d_out, N);
}